// Round 9
// baseline (470.040 us; speedup 1.0000x reference)
//
#include <hip/hip_runtime.h>
#include <hip/hip_bf16.h>

#define T_STEPS 2048
#define BATCH 16
#define DIM 1024
#define NDIM 64
#define M_TOTAL (T_STEPS * BATCH)  // 32768
#define STRIDE (BATCH * NDIM)      // floats per timestep in Kp/Qp = 1024
#define CH 32                      // recurrence chunk (timesteps per LDS buffer)
#define NC (T_STEPS / CH)

typedef __attribute__((ext_vector_type(8))) short bf16x8;
typedef __attribute__((ext_vector_type(4))) float f32x4;
typedef __attribute__((ext_vector_type(2))) float f32x2;

#define NEG_LOG2E -1.44269504088896f

__device__ inline unsigned pk_bf(float lo, float hi) {
    __hip_bfloat162 h = __float22bfloat162_rn(float2{lo, hi});
    return *(unsigned*)&h;  // v_cvt_pk_bf16_f32
}

template <int CTRL>
__device__ inline float dpp_add(float x) {
    int v = __builtin_amdgcn_update_dpp(0, __float_as_int(x), CTRL, 0xF, 0xF, true);
    return x + __int_as_float(v);
}
// full sum across contiguous 16-lane rows (result in all 16 lanes)
__device__ inline float red16(float x) {
    x = dpp_add<0xB1>(x);   // quad_perm xor1
    x = dpp_add<0x4E>(x);   // quad_perm xor2
    x = dpp_add<0x141>(x);  // row_half_mirror (xor4)
    x = dpp_add<0x140>(x);  // row_mirror (xor8)
    return x;
}
// two independent 16-lane reductions, stage-interleaved so their DPP chains overlap
__device__ inline void red16x2(float& a, float& b) {
    a = dpp_add<0xB1>(a);  b = dpp_add<0xB1>(b);
    a = dpp_add<0x4E>(a);  b = dpp_add<0x4E>(b);
    a = dpp_add<0x141>(a); b = dpp_add<0x141>(b);
    a = dpp_add<0x140>(a); b = dpp_add<0x140>(b);
}
// four independent 16-lane reductions, stage-interleaved (3-instr gaps kill DPP hazards)
__device__ inline void red16x4(float& a, float& b, float& cc, float& d) {
    a = dpp_add<0xB1>(a);  b = dpp_add<0xB1>(b);  cc = dpp_add<0xB1>(cc);  d = dpp_add<0xB1>(d);
    a = dpp_add<0x4E>(a);  b = dpp_add<0x4E>(b);  cc = dpp_add<0x4E>(cc);  d = dpp_add<0x4E>(d);
    a = dpp_add<0x141>(a); b = dpp_add<0x141>(b); cc = dpp_add<0x141>(cc); d = dpp_add<0x141>(d);
    a = dpp_add<0x140>(a); b = dpp_add<0x140>(b); cc = dpp_add<0x140>(cc); d = dpp_add<0x140>(d);
}
__device__ inline float silu_o(float o) {  // o * silu(o) = o^2 * sigmoid(o)
    float e = __builtin_amdgcn_exp2f(o * NEG_LOG2E);
    return o * o * __builtin_amdgcn_rcpf(1.f + e);
}

#define AS1 __attribute__((address_space(1)))
#define AS3 __attribute__((address_space(3)))
__device__ inline void gl_lds16(const float* g, float* l) {
    __builtin_amdgcn_global_load_lds((const AS1 unsigned*)g, (AS3 unsigned*)l, 16, 0, 0);
}
__device__ inline void gl_lds16s(const unsigned short* g, unsigned short* l) {
    __builtin_amdgcn_global_load_lds((const AS1 unsigned*)g, (AS3 unsigned*)l, 16, 0, 0);
}
__device__ inline void gl_lds4(const float* g, float* l) {
    __builtin_amdgcn_global_load_lds((const AS1 unsigned*)g, (AS3 unsigned*)l, 4, 0, 0);
}
#define WAIT_VM0 do { __builtin_amdgcn_s_waitcnt(0x0F70); asm volatile("" ::: "memory"); } while (0)

// ---------------- W prepack: fp32 -> bf16, row order [K, Q, V, A] ----------------
__global__ __launch_bounds__(256) void pack_w(
    const float* __restrict__ Wk, const float* __restrict__ Wq,
    const float* __restrict__ Wv, const float* __restrict__ Wa,
    unsigned short* __restrict__ Wb) {
    int n = blockIdx.x;  // 0..255
    int sel = n >> 6;
    const float* W = (sel == 0) ? Wk : (sel == 1) ? Wq : (sel == 2) ? Wv : Wa;
    int k4 = threadIdx.x * 4;
    float4 f = *(const float4*)(W + (size_t)(n & 63) * DIM + k4);
    uint2 u;
    u.x = pk_bf(f.x, f.y);
    u.y = pk_bf(f.z, f.w);
    *(uint2*)(Wb + (size_t)n * DIM + k4) = u;
}

// ---------------- projection: x-stationary 128x256 tile ----------------
// R9: ONE block per 128-row m-tile stages x ONCE and computes all 4 outputs
// (K,Q,V,A = 256 W rows). Halves x HBM traffic (268 -> 134 MB). 64 KB LDS,
// 2 blocks/CU. Wave wv owns n-stripe wv*64.. -> output group wv directly.
__global__ __launch_bounds__(256, 2) void proj_kernel(
    const float* __restrict__ x, const unsigned short* __restrict__ Wb,
    const float* __restrict__ ba, float* __restrict__ Kp, float* __restrict__ Qp,
    float* __restrict__ VAi) {
    __shared__ float sA[128 * 64];            // 32 KB fp32 (x tile)
    __shared__ unsigned short sB[256 * 64];   // 32 KB bf16 (all 256 W rows)

    const int m0 = blockIdx.x * 128;
    const int tid = threadIdx.x;
    const int wv = tid >> 6, lane = tid & 63, lrow = lane & 15, quad = lane >> 4;

    f32x4 acc[8][4];
#pragma unroll
    for (int a = 0; a < 8; a++)
#pragma unroll
        for (int b = 0; b < 4; b++) acc[a][b] = (f32x4)(0.f);

    // staging bases: lane-contiguous LDS dest (wave-uniform base + lane*16)
    const float* xg = x + (size_t)(m0 + (tid >> 4)) * DIM + (tid & 15) * 4;
    const unsigned short* wg = Wb + (size_t)(tid >> 3) * DIM + (tid & 7) * 8;

    for (int it = 0; it < 16; ++it) {
        const int k0 = it * 64;
        __syncthreads();  // previous iteration's frag reads done
#pragma unroll
        for (int j = 0; j < 8; ++j)  // x: 128x64 fp32 = 32 KB
            gl_lds16(xg + (size_t)(16 * j) * DIM + k0, &sA[(tid + 256 * j) * 4]);
#pragma unroll
        for (int j = 0; j < 8; ++j)  // W: 256x64 bf16 = 32 KB
            gl_lds16s(wg + (size_t)(32 * j) * DIM + k0, &sB[(tid + 256 * j) * 8]);
        WAIT_VM0;
        __syncthreads();

#pragma unroll
        for (int ks = 0; ks < 2; ++ks) {
            bf16x8 af[8];
#pragma unroll
            for (int mt = 0; mt < 8; ++mt) {
                const float* pa = &sA[(mt * 16 + lrow) * 64 + ks * 32 + quad * 8];
                float4 lo = ((const float4*)pa)[0], hi = ((const float4*)pa)[1];
                unsigned pk[4] = {pk_bf(lo.x, lo.y), pk_bf(lo.z, lo.w),
                                  pk_bf(hi.x, hi.y), pk_bf(hi.z, hi.w)};
                af[mt] = *(bf16x8*)pk;
            }
#pragma unroll
            for (int nt = 0; nt < 4; ++nt) {
                bf16x8 bfr = *(const bf16x8*)&sB[(wv * 64 + nt * 16 + lrow) * 64 + ks * 32 + quad * 8];
#pragma unroll
                for (int mt = 0; mt < 8; ++mt)
                    acc[mt][nt] = __builtin_amdgcn_mfma_f32_16x16x32_bf16(af[mt], bfr, acc[mt][nt], 0, 0, 0);
            }
        }
    }

    // epilogue: C/D layout col = lane&15, row = quad*4 + reg  [m89-verified]
    const int g2 = wv;  // 0=K 1=Q 2=V 3=A (matches pack_w row order)
    float bav[4];
    if (g2 == 3) {
#pragma unroll
        for (int nt = 0; nt < 4; ++nt) bav[nt] = ba[nt * 16 + lrow];
    }
#pragma unroll
    for (int mt = 0; mt < 8; ++mt)
#pragma unroll
        for (int nt = 0; nt < 4; ++nt) {
            int col = nt * 16 + lrow;
#pragma unroll
            for (int reg = 0; reg < 4; ++reg) {
                int m = m0 + mt * 16 + quad * 4 + reg;
                float vvv = acc[mt][nt][reg];
                if (g2 == 0) Kp[(size_t)m * 64 + col] = vvv;
                else if (g2 == 1) Qp[(size_t)m * 64 + col] = vvv;
                else if (g2 == 2) VAi[(size_t)m * 128 + col * 2] = vvv;
                else VAi[(size_t)m * 128 + col * 2 + 1] = NEG_LOG2E * (vvv + bav[nt]);
            }
        }
}

// ---------------- kq[m] = K[m,:].Q[m,:]   kk[m] = K[m,:].K[m+B,:]  (k_t . k_{t+1}) ----------------
__global__ __launch_bounds__(256) void kq_kernel(
    const float* __restrict__ Kp, const float* __restrict__ Qp,
    float* __restrict__ kq, float* __restrict__ kk) {
    int m = blockIdx.x * 16 + (threadIdx.x >> 4);
    int c = threadIdx.x & 15;
    float4 k = *(const float4*)(Kp + (size_t)m * 64 + c * 4);
    float4 q = *(const float4*)(Qp + (size_t)m * 64 + c * 4);
    float4 kn = {0.f, 0.f, 0.f, 0.f};
    if (m + BATCH < M_TOTAL) kn = *(const float4*)(Kp + (size_t)(m + BATCH) * 64 + c * 4);
    float pq = k.x * q.x + k.y * q.y + k.z * q.z + k.w * q.w;
    float pk = k.x * kn.x + k.y * kn.y + k.z * kn.z + k.w * kn.w;
    red16x2(pq, pk);
    if (c == 0) { kq[m] = pq; kk[m] = pk; }
}

// ---------------- recurrence ----------------
// grid (16 row-groups, 16 batches) x 64; lane = r*16+c; row i = g*4+r, cols c*4..+3
//
// R9 issue-diet (R5's group-LDS structure + R8's look-ahead retained):
//  - state update: S = alpha*S + beta*k, beta = (1-alpha)*v   (no w/d temporaries)
//  - rq reduction REMOVED from the step: o_t = alpha*rq + (1-alpha)*vkq is affine
//    in the lane partials, so each lane stores o^ = fma(alpha, pq_partial,
//    (1-alpha)*vkq/16); the 4 o^'s are reduced AFTER the group via red16x4
//    (4-way interleave = perfect ILP + DPP-hazard-free spacing).
//  - only the serial-path ck reduction (feeds step t+1's rk) stays in-step.
__global__ __launch_bounds__(64, 1) void recur_kernel(
    const float* __restrict__ Kp, const float* __restrict__ Qp,
    const float* __restrict__ VAi, const float* __restrict__ KQp,
    const float* __restrict__ KKp,
    const float* __restrict__ S0, const float* __restrict__ d_alpha,
    float* __restrict__ out, float* __restrict__ Sout) {
    __shared__ float Kl[2][CH][64];   // 16 KB
    __shared__ float Ql[2][CH][64];   // 16 KB
    __shared__ float VAl[2][CH][8];   // 2 KB: [t] = v0,a0,v1,a1,v2,a2,v3,a3 (rows g*4..+3)
    __shared__ float KQl[2][64];      // 0.5 KB (only [0..31] used per buffer)
    __shared__ float KKl[2][64];      // 0.5 KB
    __shared__ float OlT[4][CH];      // transposed output staging: [r][t]

    int b = blockIdx.y, g = blockIdx.x, lane = threadIdx.x;
    int r = lane >> 4, c = lane & 15, i = g * 4 + r, c4 = c * 4;

    f32x4 sv = *(const f32x4*)(S0 + ((size_t)b * NDIM + i) * NDIM + c4);
    float da2 = d_alpha[i] * NEG_LOG2E;  // alpha logit pre-scaled for exp2 form

    const float* Kbase = Kp + (size_t)b * NDIM + (size_t)(lane >> 4) * STRIDE + (lane & 15) * 4;
    const float* Qbase = Qp + (size_t)b * NDIM + (size_t)(lane >> 4) * STRIDE + (lane & 15) * 4;
    const float* VAbase = VAi + (size_t)b * 128 + g * 8 + (lane & 1) * 4 + (size_t)(lane >> 1) * 2048;
    const float* KQbase = KQp + b + (size_t)(lane & 31) * BATCH;
    const float* KKbase = KKp + b + (size_t)(lane & 31) * BATCH;

    auto load_chunk = [&](int t0, int buf) {
#pragma unroll
        for (int j = 0; j < 8; ++j) {
            gl_lds16(Kbase + (size_t)(t0 + j * 4) * STRIDE, &Kl[buf][j * 4][0]);
            gl_lds16(Qbase + (size_t)(t0 + j * 4) * STRIDE, &Ql[buf][j * 4][0]);
        }
        gl_lds16(VAbase + (size_t)t0 * 2048, &VAl[buf][0][0]);
        gl_lds4(KQbase + (size_t)t0 * BATCH, &KQl[buf][0]);
        gl_lds4(KKbase + (size_t)t0 * BATCH, &KKl[buf][0]);
    };

    // group register double-buffer (banks 0/1, all indices literal after expansion)
    f32x4 kg[2][4], qg[2][4], kqg[2], kkg[2];
    f32x2 vg[2][4];
    float og_0, og_1, og_2, og_3;
    float ee, ckm, vkk, vkq, v_cur, pqprev;

#define LOADG(gi, buf, t4_) do {                                          \
    const float* Kb_ = &Kl[buf][0][0] + (t4_) * 64 + c4;                  \
    const float* Qb_ = &Ql[buf][0][0] + (t4_) * 64 + c4;                  \
    _Pragma("unroll")                                                     \
    for (int u_ = 0; u_ < 4; ++u_) {                                      \
        kg[gi][u_] = *(const f32x4*)(Kb_ + u_ * 64);                      \
        qg[gi][u_] = *(const f32x4*)(Qb_ + u_ * 64);                      \
        vg[gi][u_] = *(const f32x2*)(&VAl[buf][0][0] + ((t4_) + u_) * 8 + r * 2); \
    }                                                                     \
    kqg[gi] = *(const f32x4*)(&KQl[buf][0] + (t4_));                      \
    kkg[gi] = *(const f32x4*)(&KKl[buf][0] + (t4_));                      \
} while (0)

// STEP for step t: kt_ = k_t, kt2_ = k_{t+2}, (qt1_,vt1_,kqt1_,kkt1_) = step-(t+1) inputs.
// Carried in: ee=exp2(z_t), ckm=ck_t - v_t*kk_t, vkk=v_t*kk_t, vkq=v_t*kq_t,
// pqprev = per-lane partial of S_{t-1}.q_t, v_cur = v_t.
#define STEP(u, kt_, kt2_, qt1_, vt1_, kqt1_, kkt1_) do {                 \
    float alpha_ = __builtin_amdgcn_rcpf(1.f + ee);                       \
    float rk1_ = fmaf(alpha_, ckm, vkk);      /* S_t.k_{t+1} */           \
    ee = __builtin_amdgcn_exp2f(fmaf(da2, rk1_, (vt1_).y));               \
    float om_ = 1.f - alpha_;                                             \
    og_##u = fmaf(alpha_, pqprev, om_ * vkq * 0.0625f);  /* lane-partial o_t */ \
    float beta_ = om_ * v_cur;                                            \
    sv = alpha_ * sv + beta_ * (kt_);         /* S_t */                   \
    f32x2 pq_ = (qt1_).lo * sv.lo; pq_ = (qt1_).hi * sv.hi + pq_;         \
    f32x2 pk_ = (kt2_).lo * sv.lo; pk_ = (kt2_).hi * sv.hi + pk_;         \
    pqprev = pq_.x + pq_.y;                                               \
    float ck_ = pk_.x + pk_.y;                                            \
    ck_ = red16(ck_);                         /* serial: feeds t+1 */     \
    float v1_ = (vt1_).x;                                                 \
    vkq = v1_ * (kqt1_); vkk = v1_ * (kkt1_);                             \
    ckm = ck_ - vkk;                                                      \
    v_cur = v1_;                                                          \
} while (0)

// group of 4 steps with bank A current and bank B holding the next group;
// batched 4-way output reduction afterwards.
#define GROUP_A(t8_) do {                                                       \
    STEP(0, kg[0][0], kg[0][2], qg[0][1], vg[0][1], kqg[0][1], kkg[0][1]);      \
    STEP(1, kg[0][1], kg[0][3], qg[0][2], vg[0][2], kqg[0][2], kkg[0][2]);      \
    STEP(2, kg[0][2], kg[1][0], qg[0][3], vg[0][3], kqg[0][3], kkg[0][3]);      \
    STEP(3, kg[0][3], kg[1][1], qg[1][0], vg[1][0], kqg[1][0], kkg[1][0]);      \
    red16x4(og_0, og_1, og_2, og_3);                                            \
    if (c == 0) *(f32x4*)(&OlT[r][t8_]) = (f32x4){og_0, og_1, og_2, og_3};      \
} while (0)
#define GROUP_B(t8_) do {                                                       \
    STEP(0, kg[1][0], kg[1][2], qg[1][1], vg[1][1], kqg[1][1], kkg[1][1]);      \
    STEP(1, kg[1][1], kg[1][3], qg[1][2], vg[1][2], kqg[1][2], kkg[1][2]);      \
    STEP(2, kg[1][2], kg[0][0], qg[1][3], vg[1][3], kqg[1][3], kkg[1][3]);      \
    STEP(3, kg[1][3], kg[0][1], qg[0][0], vg[0][0], kqg[0][0], kkg[0][0]);      \
    red16x4(og_0, og_1, og_2, og_3);                                            \
    if (c == 0) *(f32x4*)(&OlT[r][t8_]) = (f32x4){og_0, og_1, og_2, og_3};      \
} while (0)

    load_chunk(0, 0);
    WAIT_VM0;
    LOADG(0, 0, 0);
    {   // prologue: step-0 inputs from S0
        f32x2 p0 = kg[0][0].lo * sv.lo; p0 = kg[0][0].hi * sv.hi + p0;   // S0.k_0
        f32x2 p1 = qg[0][0].lo * sv.lo; p1 = qg[0][0].hi * sv.hi + p1;   // S0.q_0
        f32x2 p2 = kg[0][1].lo * sv.lo; p2 = kg[0][1].hi * sv.hi + p2;   // S0.k_1
        float rk0 = p0.x + p0.y, ck0 = p2.x + p2.y;
        pqprev = p1.x + p1.y;                 // per-lane partial (not reduced)
        red16x2(rk0, ck0);
        float v0 = vg[0][0].x;
        ee = __builtin_amdgcn_exp2f(fmaf(da2, rk0, vg[0][0].y));
        vkq = v0 * kqg[0][0];
        vkk = v0 * kkg[0][0];
        ckm = ck0 - vkk;
        v_cur = v0;
    }

#pragma unroll 1
    for (int j = 0; j < NC; ++j) {
        const int cb = j & 1, nb = cb ^ 1;
        if (j + 1 < NC) load_chunk((j + 1) * CH, nb);

#pragma unroll 1
        for (int t8 = 0; t8 < 24; t8 += 8) {
            LOADG(1, cb, t8 + 4);
            GROUP_A(t8);
            LOADG(0, cb, t8 + 8);
            GROUP_B(t8 + 4);
        }
        // last two groups: the final group's look-ahead needs next chunk's group 0
        LOADG(1, cb, 28);
        GROUP_A(24);
        WAIT_VM0;            // next-chunk staging (issued a whole chunk ago) landed
        LOADG(0, nb, 0);     // next chunk group 0 (stale-but-initialized on last chunk: dead)
        GROUP_B(28);

        if (lane < 32) {  // dump chunk outputs with fused silu: lane = local t
            float4 t4o;
            t4o.x = silu_o(OlT[0][lane]);
            t4o.y = silu_o(OlT[1][lane]);
            t4o.z = silu_o(OlT[2][lane]);
            t4o.w = silu_o(OlT[3][lane]);
            *(float4*)(out + ((size_t)(j * CH + lane) * BATCH + b) * NDIM + g * 4) = t4o;
        }
    }
#undef GROUP_A
#undef GROUP_B
#undef STEP
#undef LOADG

    *(float4*)(Sout + ((size_t)b * NDIM + i) * NDIM + c4) = float4{sv.x, sv.y, sv.z, sv.w};
}

extern "C" void kernel_launch(void* const* d_in, const int* in_sizes, int n_in,
                              void* d_out, int out_size, void* d_ws, size_t ws_size,
                              hipStream_t stream) {
    const float* x  = (const float*)d_in[0];
    const float* S0 = (const float*)d_in[1];
    const float* Wk = (const float*)d_in[2];
    const float* Wv = (const float*)d_in[3];
    const float* Wq = (const float*)d_in[4];
    const float* Wa = (const float*)d_in[5];
    const float* da = (const float*)d_in[6];
    const float* ba = (const float*)d_in[7];

    float* out = (float*)d_out;
    float* Sout = out + (size_t)T_STEPS * BATCH * NDIM;

    const size_t per = (size_t)M_TOTAL * NDIM;
    float* Kp  = (float*)d_ws;           // per floats
    float* Qp  = Kp + per;               // per
    float* VAi = Qp + per;               // 2*per (v,a interleaved per row)
    float* kq  = VAi + 2 * per;          // M_TOTAL
    float* kk  = kq + M_TOTAL;           // M_TOTAL (k_t . k_{t+1})
    unsigned short* Wb = (unsigned short*)(kk + M_TOTAL);  // 512 KB bf16

    pack_w<<<dim3(256), dim3(256), 0, stream>>>(Wk, Wq, Wv, Wa, Wb);
    proj_kernel<<<dim3(M_TOTAL / 128), dim3(256), 0, stream>>>(x, Wb, ba, Kp, Qp, VAi);
    kq_kernel<<<dim3(M_TOTAL / 16), dim3(256), 0, stream>>>(Kp, Qp, kq, kk);
    recur_kernel<<<dim3(16, BATCH), dim3(64), 0, stream>>>(Kp, Qp, VAi, kq, kk, S0, da, out, Sout);
}

// Round 10
// 438.444 us; speedup vs baseline: 1.0721x; 1.0721x over previous
//
#include <hip/hip_runtime.h>
#include <hip/hip_bf16.h>

#define T_STEPS 2048
#define BATCH 16
#define DIM 1024
#define NDIM 64
#define M_TOTAL (T_STEPS * BATCH)  // 32768
#define STRIDE (BATCH * NDIM)      // floats per timestep in Kp/Qp = 1024
#define CH 32                      // recurrence chunk (timesteps per LDS buffer)
#define NC (T_STEPS / CH)

typedef __attribute__((ext_vector_type(8))) short bf16x8;
typedef __attribute__((ext_vector_type(4))) float f32x4;
typedef __attribute__((ext_vector_type(2))) float f32x2;

#define NEG_LOG2E -1.44269504088896f

__device__ inline unsigned pk_bf(float lo, float hi) {
    __hip_bfloat162 h = __float22bfloat162_rn(float2{lo, hi});
    return *(unsigned*)&h;  // v_cvt_pk_bf16_f32
}

template <int CTRL>
__device__ inline float dpp_add(float x) {
    int v = __builtin_amdgcn_update_dpp(0, __float_as_int(x), CTRL, 0xF, 0xF, true);
    return x + __int_as_float(v);
}
// full sum across contiguous 16-lane rows (result in all 16 lanes)
__device__ inline float red16(float x) {
    x = dpp_add<0xB1>(x);   // quad_perm xor1
    x = dpp_add<0x4E>(x);   // quad_perm xor2
    x = dpp_add<0x141>(x);  // row_half_mirror (xor4)
    x = dpp_add<0x140>(x);  // row_mirror (xor8)
    return x;
}
// two independent 16-lane reductions, stage-interleaved so their DPP chains overlap
__device__ inline void red16x2(float& a, float& b) {
    a = dpp_add<0xB1>(a);  b = dpp_add<0xB1>(b);
    a = dpp_add<0x4E>(a);  b = dpp_add<0x4E>(b);
    a = dpp_add<0x141>(a); b = dpp_add<0x141>(b);
    a = dpp_add<0x140>(a); b = dpp_add<0x140>(b);
}
__device__ inline float silu_o(float o) {  // o * silu(o) = o^2 * sigmoid(o)
    float e = __builtin_amdgcn_exp2f(o * NEG_LOG2E);
    return o * o * __builtin_amdgcn_rcpf(1.f + e);
}

#define AS1 __attribute__((address_space(1)))
#define AS3 __attribute__((address_space(3)))
__device__ inline void gl_lds16(const float* g, float* l) {
    __builtin_amdgcn_global_load_lds((const AS1 unsigned*)g, (AS3 unsigned*)l, 16, 0, 0);
}
__device__ inline void gl_lds16s(const unsigned short* g, unsigned short* l) {
    __builtin_amdgcn_global_load_lds((const AS1 unsigned*)g, (AS3 unsigned*)l, 16, 0, 0);
}
__device__ inline void gl_lds4(const float* g, float* l) {
    __builtin_amdgcn_global_load_lds((const AS1 unsigned*)g, (AS3 unsigned*)l, 4, 0, 0);
}
#define WAIT_VM0 do { __builtin_amdgcn_s_waitcnt(0x0F70); asm volatile("" ::: "memory"); } while (0)

// ---------------- W prepack: fp32 -> bf16, row order [K, Q, V, A] ----------------
__global__ __launch_bounds__(256) void pack_w(
    const float* __restrict__ Wk, const float* __restrict__ Wq,
    const float* __restrict__ Wv, const float* __restrict__ Wa,
    unsigned short* __restrict__ Wb) {
    int n = blockIdx.x;  // 0..255
    int sel = n >> 6;
    const float* W = (sel == 0) ? Wk : (sel == 1) ? Wq : (sel == 2) ? Wv : Wa;
    int k4 = threadIdx.x * 4;
    float4 f = *(const float4*)(W + (size_t)(n & 63) * DIM + k4);
    uint2 u;
    u.x = pk_bf(f.x, f.y);
    u.y = pk_bf(f.z, f.w);
    *(uint2*)(Wb + (size_t)n * DIM + k4) = u;
}

// ---------------- projection: x-stationary 64x256 tile ----------------
// R10: one block per 64-row m-tile stages x ONCE for all 4 outputs (halved x HBM,
// like R9) but at grid 512 = 2 blocks/CU, 2 waves/SIMD (R9's 1-wave/SIMD MFMA
// latency exposure fixed). 48 KB LDS. Wave wv = output group (K/Q/V/A).
__global__ __launch_bounds__(256, 2) void proj_kernel(
    const float* __restrict__ x, const unsigned short* __restrict__ Wb,
    const float* __restrict__ ba, float* __restrict__ Kp, float* __restrict__ Qp,
    float* __restrict__ VAi) {
    __shared__ float sA[64 * 64];             // 16 KB fp32 (x tile)
    __shared__ unsigned short sB[256 * 64];   // 32 KB bf16 (all 256 W rows)

    const int m0 = blockIdx.x * 64;
    const int tid = threadIdx.x;
    const int wv = tid >> 6, lane = tid & 63, lrow = lane & 15, quad = lane >> 4;

    f32x4 acc[4][4];
#pragma unroll
    for (int a = 0; a < 4; a++)
#pragma unroll
        for (int b = 0; b < 4; b++) acc[a][b] = (f32x4)(0.f);

    // staging bases: lane-contiguous LDS dest (wave-uniform base + lane*16)
    const float* xg = x + (size_t)(m0 + (tid >> 4)) * DIM + (tid & 15) * 4;
    const unsigned short* wg = Wb + (size_t)(tid >> 3) * DIM + (tid & 7) * 8;

    for (int it = 0; it < 16; ++it) {
        const int k0 = it * 64;
        __syncthreads();  // previous iteration's frag reads done
#pragma unroll
        for (int j = 0; j < 4; ++j)  // x: 64x64 fp32 = 16 KB
            gl_lds16(xg + (size_t)(16 * j) * DIM + k0, &sA[(tid + 256 * j) * 4]);
#pragma unroll
        for (int j = 0; j < 8; ++j)  // W: 256x64 bf16 = 32 KB
            gl_lds16s(wg + (size_t)(32 * j) * DIM + k0, &sB[(tid + 256 * j) * 8]);
        WAIT_VM0;
        __syncthreads();

#pragma unroll
        for (int ks = 0; ks < 2; ++ks) {
            bf16x8 af[4];
#pragma unroll
            for (int mt = 0; mt < 4; ++mt) {
                const float* pa = &sA[(mt * 16 + lrow) * 64 + ks * 32 + quad * 8];
                float4 lo = ((const float4*)pa)[0], hi = ((const float4*)pa)[1];
                unsigned pk[4] = {pk_bf(lo.x, lo.y), pk_bf(lo.z, lo.w),
                                  pk_bf(hi.x, hi.y), pk_bf(hi.z, hi.w)};
                af[mt] = *(bf16x8*)pk;
            }
#pragma unroll
            for (int nt = 0; nt < 4; ++nt) {
                bf16x8 bfr = *(const bf16x8*)&sB[(wv * 64 + nt * 16 + lrow) * 64 + ks * 32 + quad * 8];
#pragma unroll
                for (int mt = 0; mt < 4; ++mt)
                    acc[mt][nt] = __builtin_amdgcn_mfma_f32_16x16x32_bf16(af[mt], bfr, acc[mt][nt], 0, 0, 0);
            }
        }
    }

    // epilogue: C/D layout col = lane&15, row = quad*4 + reg  [m89-verified]
    const int g2 = wv;  // 0=K 1=Q 2=V 3=A (matches pack_w row order)
    float bav[4];
    if (g2 == 3) {
#pragma unroll
        for (int nt = 0; nt < 4; ++nt) bav[nt] = ba[nt * 16 + lrow];
    }
#pragma unroll
    for (int mt = 0; mt < 4; ++mt)
#pragma unroll
        for (int nt = 0; nt < 4; ++nt) {
            int col = nt * 16 + lrow;
#pragma unroll
            for (int reg = 0; reg < 4; ++reg) {
                int m = m0 + mt * 16 + quad * 4 + reg;
                float vvv = acc[mt][nt][reg];
                if (g2 == 0) Kp[(size_t)m * 64 + col] = vvv;
                else if (g2 == 1) Qp[(size_t)m * 64 + col] = vvv;
                else if (g2 == 2) VAi[(size_t)m * 128 + col * 2] = vvv;
                else VAi[(size_t)m * 128 + col * 2 + 1] = NEG_LOG2E * (vvv + bav[nt]);
            }
        }
}

// ---------------- kq[m] = K[m,:].Q[m,:]   kk[m] = K[m,:].K[m+B,:]  (k_t . k_{t+1}) ----------------
__global__ __launch_bounds__(256) void kq_kernel(
    const float* __restrict__ Kp, const float* __restrict__ Qp,
    float* __restrict__ kq, float* __restrict__ kk) {
    int m = blockIdx.x * 16 + (threadIdx.x >> 4);
    int c = threadIdx.x & 15;
    float4 k = *(const float4*)(Kp + (size_t)m * 64 + c * 4);
    float4 q = *(const float4*)(Qp + (size_t)m * 64 + c * 4);
    float4 kn = {0.f, 0.f, 0.f, 0.f};
    if (m + BATCH < M_TOTAL) kn = *(const float4*)(Kp + (size_t)(m + BATCH) * 64 + c * 4);
    float pq = k.x * q.x + k.y * q.y + k.z * q.z + k.w * q.w;
    float pk = k.x * kn.x + k.y * kn.y + k.z * kn.z + k.w * kn.w;
    red16x2(pq, pk);
    if (c == 0) { kq[m] = pq; kk[m] = pk; }
}

// ---------------- recurrence (exact R8 revert: measured 211.0 µs) ----------------
// grid (16 row-groups, 16 batches) x 64; lane = r*16+c; row i = g*4+r, cols c*4..+3
// Group-batched LDS loads (R5) + option-A look-ahead (R8). red16x2 stays in-step
// (R9 showed batching the reductions lengthens the serial span).
__global__ __launch_bounds__(64, 1) void recur_kernel(
    const float* __restrict__ Kp, const float* __restrict__ Qp,
    const float* __restrict__ VAi, const float* __restrict__ KQp,
    const float* __restrict__ KKp,
    const float* __restrict__ S0, const float* __restrict__ d_alpha,
    float* __restrict__ out, float* __restrict__ Sout) {
    __shared__ float Kl[2][CH][64];   // 16 KB
    __shared__ float Ql[2][CH][64];   // 16 KB
    __shared__ float VAl[2][CH][8];   // 2 KB: [t] = v0,a0,v1,a1,v2,a2,v3,a3 (rows g*4..+3)
    __shared__ float KQl[2][64];      // 0.5 KB (only [0..31] used per buffer)
    __shared__ float KKl[2][64];      // 0.5 KB
    __shared__ float OlT[4][CH];      // transposed output staging: [r][t]

    int b = blockIdx.y, g = blockIdx.x, lane = threadIdx.x;
    int r = lane >> 4, c = lane & 15, i = g * 4 + r, c4 = c * 4;

    f32x4 sv = *(const f32x4*)(S0 + ((size_t)b * NDIM + i) * NDIM + c4);
    float da2 = d_alpha[i] * NEG_LOG2E;  // alpha logit pre-scaled for exp2 form

    const float* Kbase = Kp + (size_t)b * NDIM + (size_t)(lane >> 4) * STRIDE + (lane & 15) * 4;
    const float* Qbase = Qp + (size_t)b * NDIM + (size_t)(lane >> 4) * STRIDE + (lane & 15) * 4;
    const float* VAbase = VAi + (size_t)b * 128 + g * 8 + (lane & 1) * 4 + (size_t)(lane >> 1) * 2048;
    const float* KQbase = KQp + b + (size_t)(lane & 31) * BATCH;
    const float* KKbase = KKp + b + (size_t)(lane & 31) * BATCH;

    auto load_chunk = [&](int t0, int buf) {
#pragma unroll
        for (int j = 0; j < 8; ++j) {
            gl_lds16(Kbase + (size_t)(t0 + j * 4) * STRIDE, &Kl[buf][j * 4][0]);
            gl_lds16(Qbase + (size_t)(t0 + j * 4) * STRIDE, &Ql[buf][j * 4][0]);
        }
        gl_lds16(VAbase + (size_t)t0 * 2048, &VAl[buf][0][0]);
        gl_lds4(KQbase + (size_t)t0 * BATCH, &KQl[buf][0]);
        gl_lds4(KKbase + (size_t)t0 * BATCH, &KKl[buf][0]);
    };

    // group register double-buffer (banks 0/1, all indices literal after expansion)
    f32x4 kg[2][4], qg[2][4], kqg[2], kkg[2];
    f32x2 vg[2][4];
    f32x4 og;
    float ee, ckm, rqm, vkk, vkq, v_cur;

#define LOADG(gi, buf, t4_) do {                                          \
    const float* Kb_ = &Kl[buf][0][0] + (t4_) * 64 + c4;                  \
    const float* Qb_ = &Ql[buf][0][0] + (t4_) * 64 + c4;                  \
    _Pragma("unroll")                                                     \
    for (int u_ = 0; u_ < 4; ++u_) {                                      \
        kg[gi][u_] = *(const f32x4*)(Kb_ + u_ * 64);                      \
        qg[gi][u_] = *(const f32x4*)(Qb_ + u_ * 64);                      \
        vg[gi][u_] = *(const f32x2*)(&VAl[buf][0][0] + ((t4_) + u_) * 8 + r * 2); \
    }                                                                     \
    kqg[gi] = *(const f32x4*)(&KQl[buf][0] + (t4_));                      \
    kkg[gi] = *(const f32x4*)(&KKl[buf][0] + (t4_));                      \
} while (0)

// STEP for step t: kt_ = k_t, kt2_ = k_{t+2}, (qt1_,vt1_,kqt1_,kkt1_) = step-(t+1) inputs.
#define STEP(u, kt_, kt2_, qt1_, vt1_, kqt1_, kkt1_) do {                 \
    float alpha_ = __builtin_amdgcn_rcpf(1.f + ee);                       \
    float rk1_ = fmaf(alpha_, ckm, vkk);      /* S_t.k_{t+1} */           \
    ee = __builtin_amdgcn_exp2f(fmaf(da2, rk1_, (vt1_).y));               \
    float o_ = fmaf(alpha_, rqm, vkq);        /* S_t.q_t */               \
    f32x4 w_ = v_cur * (kt_);                                             \
    f32x4 d_ = sv - w_;                                                   \
    sv = w_ + alpha_ * d_;                    /* S_t */                   \
    f32x2 pq_ = (qt1_).lo * sv.lo; pq_ = (qt1_).hi * sv.hi + pq_;         \
    f32x2 pk_ = (kt2_).lo * sv.lo; pk_ = (kt2_).hi * sv.hi + pk_;         \
    float rq_ = pq_.x + pq_.y, ck_ = pk_.x + pk_.y;                       \
    red16x2(rq_, ck_);                        /* for step t+1 */          \
    float v1_ = (vt1_).x;                                                 \
    vkq = v1_ * (kqt1_); vkk = v1_ * (kkt1_);                             \
    rqm = rq_ - vkq; ckm = ck_ - vkk;                                     \
    og[u] = o_;                                                           \
    v_cur = v1_;                                                          \
} while (0)

// group of 4 steps with bank A current and bank B holding the next group
#define GROUP_A() do {                                                          \
    STEP(0, kg[0][0], kg[0][2], qg[0][1], vg[0][1], kqg[0][1], kkg[0][1]);      \
    STEP(1, kg[0][1], kg[0][3], qg[0][2], vg[0][2], kqg[0][2], kkg[0][2]);      \
    STEP(2, kg[0][2], kg[1][0], qg[0][3], vg[0][3], kqg[0][3], kkg[0][3]);      \
    STEP(3, kg[0][3], kg[1][1], qg[1][0], vg[1][0], kqg[1][0], kkg[1][0]);      \
} while (0)
#define GROUP_B() do {                                                          \
    STEP(0, kg[1][0], kg[1][2], qg[1][1], vg[1][1], kqg[1][1], kkg[1][1]);      \
    STEP(1, kg[1][1], kg[1][3], qg[1][2], vg[1][2], kqg[1][2], kkg[1][2]);      \
    STEP(2, kg[1][2], kg[0][0], qg[1][3], vg[1][3], kqg[1][3], kkg[1][3]);      \
    STEP(3, kg[1][3], kg[0][1], qg[0][0], vg[0][0], kqg[0][0], kkg[0][0]);      \
} while (0)

    load_chunk(0, 0);
    WAIT_VM0;
    LOADG(0, 0, 0);
    {   // prologue: step-0 inputs from S0
        f32x2 p0 = kg[0][0].lo * sv.lo; p0 = kg[0][0].hi * sv.hi + p0;   // S0.k_0
        f32x2 p1 = qg[0][0].lo * sv.lo; p1 = qg[0][0].hi * sv.hi + p1;   // S0.q_0
        f32x2 p2 = kg[0][1].lo * sv.lo; p2 = kg[0][1].hi * sv.hi + p2;   // S0.k_1
        float rk0 = p0.x + p0.y, rq0 = p1.x + p1.y, ck0 = p2.x + p2.y;
        red16x2(rk0, rq0);
        ck0 = red16(ck0);
        float v0 = vg[0][0].x;
        ee = __builtin_amdgcn_exp2f(fmaf(da2, rk0, vg[0][0].y));
        vkq = v0 * kqg[0][0];
        vkk = v0 * kkg[0][0];
        rqm = rq0 - vkq;
        ckm = ck0 - vkk;
        v_cur = v0;
    }

#pragma unroll 1
    for (int j = 0; j < NC; ++j) {
        const int cb = j & 1, nb = cb ^ 1;
        if (j + 1 < NC) load_chunk((j + 1) * CH, nb);

#pragma unroll 1
        for (int t8 = 0; t8 < 24; t8 += 8) {
            LOADG(1, cb, t8 + 4);
            GROUP_A();
            if (c == 0) *(f32x4*)(&OlT[r][t8]) = og;
            LOADG(0, cb, t8 + 8);
            GROUP_B();
            if (c == 0) *(f32x4*)(&OlT[r][t8 + 4]) = og;
        }
        // last two groups: the final group's look-ahead needs next chunk's group 0
        LOADG(1, cb, 28);
        GROUP_A();
        if (c == 0) *(f32x4*)(&OlT[r][24]) = og;
        WAIT_VM0;            // next-chunk staging (issued a whole chunk ago) landed
        LOADG(0, nb, 0);     // next chunk group 0 (stale-but-initialized on last chunk: dead)
        GROUP_B();
        if (c == 0) *(f32x4*)(&OlT[r][28]) = og;

        if (lane < 32) {  // dump chunk outputs with fused silu: lane = local t
            float4 t4o;
            t4o.x = silu_o(OlT[0][lane]);
            t4o.y = silu_o(OlT[1][lane]);
            t4o.z = silu_o(OlT[2][lane]);
            t4o.w = silu_o(OlT[3][lane]);
            *(float4*)(out + ((size_t)(j * CH + lane) * BATCH + b) * NDIM + g * 4) = t4o;
        }
    }
#undef GROUP_A
#undef GROUP_B
#undef STEP
#undef LOADG

    *(float4*)(Sout + ((size_t)b * NDIM + i) * NDIM + c4) = float4{sv.x, sv.y, sv.z, sv.w};
}

extern "C" void kernel_launch(void* const* d_in, const int* in_sizes, int n_in,
                              void* d_out, int out_size, void* d_ws, size_t ws_size,
                              hipStream_t stream) {
    const float* x  = (const float*)d_in[0];
    const float* S0 = (const float*)d_in[1];
    const float* Wk = (const float*)d_in[2];
    const float* Wv = (const float*)d_in[3];
    const float* Wq = (const float*)d_in[4];
    const float* Wa = (const float*)d_in[5];
    const float* da = (const float*)d_in[6];
    const float* ba = (const float*)d_in[7];

    float* out = (float*)d_out;
    float* Sout = out + (size_t)T_STEPS * BATCH * NDIM;

    const size_t per = (size_t)M_TOTAL * NDIM;
    float* Kp  = (float*)d_ws;           // per floats
    float* Qp  = Kp + per;               // per
    float* VAi = Qp + per;               // 2*per (v,a interleaved per row)
    float* kq  = VAi + 2 * per;          // M_TOTAL
    float* kk  = kq + M_TOTAL;           // M_TOTAL (k_t . k_{t+1})
    unsigned short* Wb = (unsigned short*)(kk + M_TOTAL);  // 512 KB bf16

    pack_w<<<dim3(256), dim3(256), 0, stream>>>(Wk, Wq, Wv, Wa, Wb);
    proj_kernel<<<dim3(M_TOTAL / 64), dim3(256), 0, stream>>>(x, Wb, ba, Kp, Qp, VAi);
    kq_kernel<<<dim3(M_TOTAL / 16), dim3(256), 0, stream>>>(Kp, Qp, kq, kk);
    recur_kernel<<<dim3(16, BATCH), dim3(64), 0, stream>>>(Kp, Qp, VAi, kq, kk, S0, da, out, Sout);
}